// Round 6
// baseline (680.110 us; speedup 1.0000x reference)
//
#include <hip/hip_runtime.h>
#include <math.h>

typedef __attribute__((ext_vector_type(8))) short short8;
typedef __attribute__((ext_vector_type(4))) float f32x4;

namespace {
constexpr int B_ = 8;
constexpr int N_ = 2048;
constexpr int D_ = 1024;
constexpr float NEGV = -1.0e9f;
}

__device__ __forceinline__ unsigned short f2bf(float x) {
    union { float f; unsigned u; } v; v.f = x;
    unsigned u = v.u + 0x7fffu + ((v.u >> 16) & 1u);
    return (unsigned short)(u >> 16);
}

// ---------------------------------------------------------------------------
// Per-batch valid lengths from the prefix mask (uint8 or int32 layout).
// ---------------------------------------------------------------------------
__global__ __launch_bounds__(256)
void k_lengths(const unsigned char* __restrict__ mask, int* __restrict__ L)
{
    const int b = blockIdx.x;
    const int t = threadIdx.x;
    const bool u8 = (mask[1] != 0);
    int cnt = 0;
    if (u8) {
        for (int n = t; n < N_; n += 256)
            cnt += (mask[(size_t)b * N_ + n] != 0) ? 1 : 0;
    } else {
        const int* mi = (const int*)mask;
        for (int n = t; n < N_; n += 256)
            cnt += (mi[(size_t)b * N_ + n] != 0) ? 1 : 0;
    }
    __shared__ int red[256];
    red[t] = cnt;
    __syncthreads();
    for (int s = 128; s > 0; s >>= 1) {
        if (t < s) red[t] += red[t + s];
        __syncthreads();
    }
    if (t == 0) L[b] = red[0];
}

// ---------------------------------------------------------------------------
// f32 -> bf16 conversion (with optional scale), 1 float4 per thread.
// ---------------------------------------------------------------------------
__global__ __launch_bounds__(256)
void convert_bf16(const float* __restrict__ in, unsigned short* __restrict__ out,
                  int n4, float alpha)
{
    const int i = blockIdx.x * 256 + threadIdx.x;
    if (i >= n4) return;
    const float4 v = ((const float4*)in)[i];
    ushort4 o;
    o.x = f2bf(v.x * alpha); o.y = f2bf(v.y * alpha);
    o.z = f2bf(v.z * alpha); o.w = f2bf(v.w * alpha);
    ((ushort4*)out)[i] = o;
}

// ---------------------------------------------------------------------------
// 256x256 pipelined bf16 NT-GEMM (C[m][n] = sum_k A[m][k]*B[n][k]).
//
// 512 threads = 8 waves (2 Mrow x 4 Ncol), per-wave 128x64 output,
// 16x16x32 MFMA, BK=32, 4-deep LDS buffering (128 KiB), counted vmcnt.
//
// ROUND-6: rounds 4/5 were stuck at MfmaUtil ~34% because the compute region
// was PINNED: asm lgkmcnt(0)+sched_barrier forced [all ds_read drains] THEN
// [all MFMA] per phase, serializing LDS (~1150cy/K-tile CU-wide) with MFMA
// (~1240cy/SIMD) -> ~860 TF structural floor (matches measured 825).
// Fix: NO asm waits inside the compute region; ds_reads and MFMAs live in one
// schedulable region so hipcc emits fine-grained counted lgkmcnt (its default,
// per m97 asm) and the LDS drain overlaps the matrix pipe. One lgkmcnt(0)
// only at the END of compute (raw s_barrier doesn't drain; the next-iter
// stage overwrites buf (kt-1)&3, so reads must be sealed before BAR_B).
//
// Per K-tile kt (buf d = kt&3):
//   [stage B,A of tile kt+3 -> buf (kt+3)&3]  + vmcnt(8)   (tails: 4 / 0)
//   BAR_A   (tile kt+1 now resident for next iter; kt was sealed last iter)
//   12 ds_read_b128 (bQ0-3, aQ0-7) + 32 MFMA   <- compiler-scheduled overlap
//   lgkmcnt(0); BAR_B   (buf (kt)&3... reads sealed; (kt+3)&3 recyclable)
// vmcnt ledger: after stage at iter kt, outstanding = tiles kt+1..kt+3 (12
// loads); vmcnt(8) drains tile kt+1 -> resident one full iteration before
// its BAR_A. WAR: stage at iter kt targets buf (kt-1)&3, last read in iter
// kt-1 and sealed by BAR_B(kt-1) which precedes this stage. Requires NT>=4.
//
// LDS rows are 64 B (4 x 16B segs). Seg swizzle: phys = logical ^ ((row>>1)&3)
// -> quarter-wave ds_read_b128 lands 2-way on banks (free, m136); staging
// pre-swizzles the GLOBAL source seg, LDS dest linear (gload_lds rule).
// Measured 0 bank conflicts.
//
// OUT_MODE: 0 = f32, 1 = bf16, 2 = f32 with prefix mask (logits):
//   m0 >= Lb -> return with NO writes (softmax writes those rows whole);
//   n0 >= Lb -> NEGV fill, no compute.
// XCD swizzle: bijective chunking, n-fastest within chunk (B-panel L2-hot).
// ---------------------------------------------------------------------------
template <int OUT_MODE>
__global__ __launch_bounds__(512, 2)
void gemm_nt_256(const unsigned short* __restrict__ A, int lda, long strideA,
                 const unsigned short* __restrict__ Bm, int ldb, long strideB,
                 void* __restrict__ Cout, int ldc, long strideC,
                 int K, const int* __restrict__ Lp)
{
    __shared__ __attribute__((aligned(16))) short As[4][8192];
    __shared__ __attribute__((aligned(16))) short Bs[4][8192];

    const int tid  = threadIdx.x;
    const int lane = tid & 63;
    const int wave = tid >> 6;
    const int wr   = wave >> 2;   // 0..1
    const int wc   = wave & 3;    // 0..3

    // ---- XCD-aware bijective block swizzle (n-fastest within chunk) ----
    const unsigned gx   = gridDim.x;
    const unsigned gxy  = gx * gridDim.y;
    const unsigned total = gxy * gridDim.z;
    const unsigned orig = blockIdx.x + gx * blockIdx.y + gxy * blockIdx.z;
    unsigned wg = orig;
    if ((total & 7u) == 0u)
        wg = (orig & 7u) * (total >> 3) + (orig >> 3);
    const unsigned bz  = wg / gxy;
    const unsigned rem = wg - bz * gxy;
    const unsigned byy = rem / gx;
    const unsigned bxx = rem - byy * gx;

    const int b  = (int)bz;
    const int m0 = (int)byy * 256;
    const int n0 = (int)bxx * 256;

    int Lb = 0;
    if (OUT_MODE == 2) {
        Lb = Lp[b];
        if (m0 >= Lb) return;   // softmax writes these rows entirely (const)
        if (n0 >= Lb) {
            // masked columns of valid rows: NEGV fill, no compute
            float* C = (float*)Cout + (long)b * strideC;
            const float4 nv = make_float4(NEGV, NEGV, NEGV, NEGV);
            const int rl = tid >> 6;          // 0..7
            const int c4 = (tid & 63) * 4;    // 0..252
#pragma unroll
            for (int l = 0; l < 32; ++l)
                *(float4*)(C + (long)(m0 + l * 8 + rl) * ldc + n0 + c4) = nv;
            return;
        }
    }

    const unsigned short* Ab = A  + (long)b * strideA;
    const unsigned short* Bb = Bm + (long)b * strideB;

    // staging: one STAGE (2 gload_lds/wave) covers 128 rows x 64 B.
    // chunk = tid: row = tid>>2, phys seg = tid&3; pre-swizzled global seg:
    const int srow = tid >> 2;                               // 0..127
    const int sseg = ((tid & 3) ^ ((tid >> 3) & 3)) * 8;     // shorts
    const unsigned short* gA = Ab + (long)(m0 + srow) * lda + sseg;
    const unsigned short* gB = Bb + (long)(n0 + srow) * ldb + sseg;
    const int ldst = (tid & ~63) * 8;   // wave-uniform LDS chunk base (shorts)

    // fragment reads: row = base + r, phys seg = q ^ ((r>>1)&3)
    const int q  = lane >> 4, r = lane & 15;
    const int arb = (wr * 128 + r) * 32;
    const int brb = (wc * 64 + r) * 32;
    const int pk  = (q ^ ((r >> 1) & 3)) * 8;

    const int NT = K >> 5;   // K-tiles of 32 (NT in {32,64} here)

    short8 aQ[8];
    short8 bQ[4];
    f32x4  acc[8][4] = {};

#define STAGE_A(dd, kt) do {                                                   \
    __builtin_amdgcn_global_load_lds(                                          \
        (const __attribute__((address_space(1))) void*)(gA + (long)(kt)*32),   \
        (__attribute__((address_space(3))) void*)(&As[dd][ldst]), 16, 0, 0);   \
    __builtin_amdgcn_global_load_lds(                                          \
        (const __attribute__((address_space(1))) void*)(gA + (long)128*lda + (long)(kt)*32), \
        (__attribute__((address_space(3))) void*)(&As[dd][4096 + ldst]), 16, 0, 0);          \
} while (0)

#define STAGE_B(dd, kt) do {                                                   \
    __builtin_amdgcn_global_load_lds(                                          \
        (const __attribute__((address_space(1))) void*)(gB + (long)(kt)*32),   \
        (__attribute__((address_space(3))) void*)(&Bs[dd][ldst]), 16, 0, 0);   \
    __builtin_amdgcn_global_load_lds(                                          \
        (const __attribute__((address_space(1))) void*)(gB + (long)128*ldb + (long)(kt)*32), \
        (__attribute__((address_space(3))) void*)(&Bs[dd][4096 + ldst]), 16, 0, 0);          \
} while (0)

#define BARX __builtin_amdgcn_s_barrier()
#define WAIT_LGKM0 do { asm volatile("s_waitcnt lgkmcnt(0)" ::: "memory"); \
                        __builtin_amdgcn_sched_barrier(0); } while (0)
#define WAIT_VM0   do { asm volatile("s_waitcnt vmcnt(0)"   ::: "memory"); \
                        __builtin_amdgcn_sched_barrier(0); } while (0)
#define WAIT_VM4   do { asm volatile("s_waitcnt vmcnt(4)"   ::: "memory"); \
                        __builtin_amdgcn_sched_barrier(0); } while (0)
#define WAIT_VM8   do { asm volatile("s_waitcnt vmcnt(8)"   ::: "memory"); \
                        __builtin_amdgcn_sched_barrier(0); } while (0)

    // prologue: stage tiles 0,1,2 (B then A each); drain tile 0 (8 stay in flight).
    STAGE_B(0, 0); STAGE_A(0, 0);
    STAGE_B(1, 1); STAGE_A(1, 1);
    STAGE_B(2, 2); STAGE_A(2, 2);
    WAIT_VM8;

    for (int kt = 0; kt < NT; ++kt) {
        const int d  = kt & 3;
        const int dn = (kt + 3) & 3;

        if (kt + 3 < NT) {
            STAGE_B(dn, kt + 3);
            STAGE_A(dn, kt + 3);
            WAIT_VM8;
        } else if (kt + 3 == NT) {
            WAIT_VM4;
        } else {
            WAIT_VM0;
        }
        BARX;   // tile kt resident everywhere (drained by iter kt-1 / prologue)

        // ---- compute region: NO asm waits; compiler overlaps LDS & MFMA ----
#pragma unroll
        for (int nr = 0; nr < 4; ++nr)
            bQ[nr] = *(const short8*)&Bs[d][brb + nr * 512 + pk];
#pragma unroll
        for (int mr = 0; mr < 8; ++mr)
            aQ[mr] = *(const short8*)&As[d][arb + mr * 512 + pk];

        __builtin_amdgcn_s_setprio(1);
#pragma unroll
        for (int mr = 0; mr < 8; ++mr)
#pragma unroll
            for (int nr = 0; nr < 4; ++nr)
                acc[mr][nr] = __builtin_amdgcn_mfma_f32_16x16x32_bf16(
                    aQ[mr], bQ[nr], acc[mr][nr], 0, 0, 0);
        __builtin_amdgcn_s_setprio(0);

        WAIT_LGKM0;   // seal this tile's ds_reads before buffer recycling
        BARX;
    }

#undef STAGE_A
#undef STAGE_B
#undef BARX
#undef WAIT_LGKM0
#undef WAIT_VM0
#undef WAIT_VM4
#undef WAIT_VM8

    // epilogue: C/D layout col = lane&15 (=r), row = (lane>>4)*4 + reg (=q*4+rr)
    const int rbase = m0 + wr * 128;
    const int cbase = n0 + wc * 64;
    if (OUT_MODE == 1) {
        unsigned short* C = (unsigned short*)Cout + (long)b * strideC;
#pragma unroll
        for (int mt = 0; mt < 8; ++mt)
#pragma unroll
            for (int nt = 0; nt < 4; ++nt)
#pragma unroll
                for (int rr = 0; rr < 4; ++rr) {
                    const int grow = rbase + mt * 16 + q * 4 + rr;
                    const int gcol = cbase + nt * 16 + r;
                    C[(long)grow * ldc + gcol] = f2bf(acc[mt][nt][rr]);
                }
    } else if (OUT_MODE == 0) {
        float* C = (float*)Cout + (long)b * strideC;
#pragma unroll
        for (int mt = 0; mt < 8; ++mt)
#pragma unroll
            for (int nt = 0; nt < 4; ++nt)
#pragma unroll
                for (int rr = 0; rr < 4; ++rr) {
                    const int grow = rbase + mt * 16 + q * 4 + rr;
                    const int gcol = cbase + nt * 16 + r;
                    C[(long)grow * ldc + gcol] = acc[mt][nt][rr];
                }
    } else {
        float* C = (float*)Cout + (long)b * strideC;
#pragma unroll
        for (int mt = 0; mt < 8; ++mt)
#pragma unroll
            for (int nt = 0; nt < 4; ++nt)
#pragma unroll
                for (int rr = 0; rr < 4; ++rr) {
                    const int grow = rbase + mt * 16 + q * 4 + rr;
                    const int gcol = cbase + nt * 16 + r;
                    const float val = (grow < Lb && gcol < Lb) ? acc[mt][nt][rr] : NEGV;
                    C[(long)grow * ldc + gcol] = val;
                }
    }
}

// ---------------------------------------------------------------------------
// In-place row softmax over last dim (N_=2048). One block per row.
// Rows >= Lb are fully masked -> softmax is exactly 1/2048: write const,
// no read (also lets the logits GEMM skip those tiles entirely).
// ---------------------------------------------------------------------------
__global__ __launch_bounds__(256)
void softmax_rows(float* __restrict__ Att, const int* __restrict__ Lp)
{
    const size_t row = blockIdx.x;
    const int i = (int)(row & (N_ - 1));
    const int b = (int)(row >> 11);
    float* p = Att + row * (size_t)N_;
    const int t = threadIdx.x;

    if (i >= Lp[b]) {
        const float c = 1.0f / 2048.0f;
        const float4 cv = make_float4(c, c, c, c);
        *(float4*)(p + t * 4)        = cv;
        *(float4*)(p + 1024 + t * 4) = cv;
        return;
    }

    float4 v0 = *(float4*)(p + t * 4);
    float4 v1 = *(float4*)(p + 1024 + t * 4);

    float mx = fmaxf(fmaxf(fmaxf(v0.x, v0.y), fmaxf(v0.z, v0.w)),
                     fmaxf(fmaxf(v1.x, v1.y), fmaxf(v1.z, v1.w)));
#pragma unroll
    for (int o = 32; o > 0; o >>= 1) mx = fmaxf(mx, __shfl_xor(mx, o, 64));

    __shared__ float red[8];
    const int wv = t >> 6;
    if ((t & 63) == 0) red[wv] = mx;
    __syncthreads();
    mx = fmaxf(fmaxf(red[0], red[1]), fmaxf(red[2], red[3]));

    float e[8];
    e[0] = expf(v0.x - mx); e[1] = expf(v0.y - mx);
    e[2] = expf(v0.z - mx); e[3] = expf(v0.w - mx);
    e[4] = expf(v1.x - mx); e[5] = expf(v1.y - mx);
    e[6] = expf(v1.z - mx); e[7] = expf(v1.w - mx);
    float s = ((e[0] + e[1]) + (e[2] + e[3])) + ((e[4] + e[5]) + (e[6] + e[7]));
#pragma unroll
    for (int o = 32; o > 0; o >>= 1) s += __shfl_xor(s, o, 64);
    if ((t & 63) == 0) red[4 + wv] = s;
    __syncthreads();
    const float inv = 1.0f / (red[4] + red[5] + red[6] + red[7]);

    *(float4*)(p + t * 4)        = make_float4(e[0] * inv, e[1] * inv, e[2] * inv, e[3] * inv);
    *(float4*)(p + 1024 + t * 4) = make_float4(e[4] * inv, e[5] * inv, e[6] * inv, e[7] * inv);
}

// ---------------------------------------------------------------------------
// att f32 [b][j][i] -> attT bf16 [b][i][j], 64x64 LDS tile transpose.
// ---------------------------------------------------------------------------
__global__ __launch_bounds__(256)
void transpose_att_bf16(const float* __restrict__ att, unsigned short* __restrict__ attT)
{
    __shared__ float tile[64][65];
    const int b  = blockIdx.z;
    const int j0 = blockIdx.y * 64;
    const int i0 = blockIdx.x * 64;
    const float* src = att + (long)b * N_ * N_;
    unsigned short* dst = attT + (long)b * N_ * N_;
    const int t = threadIdx.x;
#pragma unroll
    for (int l = 0; l < 4; ++l) {
        const int idx = t + l * 256;
        const int jj = idx >> 4;
        const int i4 = (idx & 15) * 4;
        const float4 v = *(const float4*)(src + (long)(j0 + jj) * N_ + i0 + i4);
        tile[i4 + 0][jj] = v.x;
        tile[i4 + 1][jj] = v.y;
        tile[i4 + 2][jj] = v.z;
        tile[i4 + 3][jj] = v.w;
    }
    __syncthreads();
#pragma unroll
    for (int l = 0; l < 4; ++l) {
        const int idx = t + l * 256;
        const int ii = idx >> 4;
        const int j4 = (idx & 15) * 4;
        ushort4 o;
        o.x = f2bf(tile[ii][j4 + 0]);
        o.y = f2bf(tile[ii][j4 + 1]);
        o.z = f2bf(tile[ii][j4 + 2]);
        o.w = f2bf(tile[ii][j4 + 3]);
        *(ushort4*)(dst + (long)(i0 + ii) * N_ + j0 + j4) = o;
    }
}

// ---------------------------------------------------------------------------
// V slice of QKV [16384 tokens][3072] (cols 2048..3071) -> VT bf16 [1024][16384]
// ---------------------------------------------------------------------------
__global__ __launch_bounds__(256)
void transpose_v_bf16(const unsigned short* __restrict__ qkv, unsigned short* __restrict__ vt)
{
    __shared__ unsigned short tile[64][68];
    const int j0 = blockIdx.x * 64;
    const int d0 = blockIdx.y * 64;
    const int t = threadIdx.x;
#pragma unroll
    for (int l = 0; l < 4; ++l) {
        const int idx = t + l * 256;
        const int jj = idx >> 4;
        const int d4 = (idx & 15) * 4;
        const ushort4 v = *(const ushort4*)(qkv + (long)(j0 + jj) * 3072 + 2048 + d0 + d4);
        tile[d4 + 0][jj] = v.x;
        tile[d4 + 1][jj] = v.y;
        tile[d4 + 2][jj] = v.z;
        tile[d4 + 3][jj] = v.w;
    }
    __syncthreads();
#pragma unroll
    for (int l = 0; l < 4; ++l) {
        const int idx = t + l * 256;
        const int dd = idx >> 4;
        const int j4 = (idx & 15) * 4;
        ushort4 o;
        o.x = tile[dd][j4 + 0];
        o.y = tile[dd][j4 + 1];
        o.z = tile[dd][j4 + 2];
        o.w = tile[dd][j4 + 3];
        *(ushort4*)(vt + (long)(d0 + dd) * 16384 + j0 + j4) = o;
    }
}

// ---------------------------------------------------------------------------
extern "C" void kernel_launch(void* const* d_in, const int* in_sizes, int n_in,
                              void* d_out, int out_size, void* d_ws, size_t ws_size,
                              hipStream_t stream)
{
    const float* x  = (const float*)d_in[0];
    const unsigned char* mask = (const unsigned char*)d_in[1];
    const float* Wq = (const float*)d_in[2];
    const float* Wk = (const float*)d_in[3];
    const float* Wv = (const float*)d_in[4];
    const float* Wo = (const float*)d_in[5];

    float* y   = (float*)d_out;                          // [B,N,D] f32
    float* att = (float*)d_out + (size_t)B_ * N_ * D_;   // [B,N,N] f32

    char* ws = (char*)d_ws;
    int* L = (int*)ws;
    unsigned short* Wqkvb = (unsigned short*)(ws + 256); // [3072,1024] (Q|K|V rows)
    unsigned short* Wob   = Wqkvb + 3145728;             // [1024,1024]
    unsigned short* xb    = Wob + 1048576;               // [16384,1024]
    unsigned short* QKVb  = xb + 16777216;               // [16384,3072]
    unsigned short* VT    = QKVb + 50331648;             // [1024,16384]
    unsigned short* attT  = QKVb;                        // [B,N,N] bf16 (reuses QKV)
    unsigned short* ctx   = xb;                          // [16384,1024] bf16 (reuses xb)

    const dim3 blk(256);
    const dim3 blk512(512);
    const long NN = (long)N_ * N_;
    const long ND = (long)N_ * D_;
    const long NQ = (long)N_ * 3072;

    k_lengths<<<dim3(B_), blk, 0, stream>>>(mask, L);

    convert_bf16<<<dim3(16384), blk, 0, stream>>>(x,  xb,  4194304, 1.0f);
    convert_bf16<<<dim3(1024),  blk, 0, stream>>>(Wq, Wqkvb,           262144, 0.06f);
    convert_bf16<<<dim3(1024),  blk, 0, stream>>>(Wk, Wqkvb + 1048576, 262144, 1.0f);
    convert_bf16<<<dim3(1024),  blk, 0, stream>>>(Wv, Wqkvb + 2097152, 262144, 1.0f);
    convert_bf16<<<dim3(1024),  blk, 0, stream>>>(Wo, Wob,             262144, 1.0f);

    // Fused QKV = x @ [Wq*0.06 | Wk | Wv]^T -> [16384, 3072] bf16
    gemm_nt_256<1><<<dim3(12, 64, 1), blk512, 0, stream>>>(
        xb, D_, 0, Wqkvb, D_, 0, QKVb, 3072, 0, D_, nullptr);

    // VT[d][b*N+j] = V[b*N+j][d]
    transpose_v_bf16<<<dim3(256, 16), blk, 0, stream>>>(QKVb, VT);

    // logits = Q K^T with prefix mask (f32 out into att region)
    gemm_nt_256<2><<<dim3(8, 8, B_), blk512, 0, stream>>>(
        QKVb, 3072, NQ, QKVb + 1024, 3072, NQ, att, N_, NN, D_, L);

    softmax_rows<<<dim3(B_ * N_), blk, 0, stream>>>(att, L);

    // attT bf16 (reuses QKV space; Q/K/V all consumed by now)
    transpose_att_bf16<<<dim3(32, 32, B_), blk, 0, stream>>>(att, attT);

    // ctx[b][i][d] = sum_j attT[b][i][j] * VT[d][b*N + j]
    gemm_nt_256<1><<<dim3(4, 8, B_), blk512, 0, stream>>>(
        attT, N_, NN, VT, B_ * N_, N_, ctx, D_, ND, N_, nullptr);

    // y = ctx Wo^T (f32 out)
    gemm_nt_256<0><<<dim3(4, 64, 1), blk512, 0, stream>>>(
        ctx, D_, 0, Wob, D_, 0, y, D_, 0, D_, nullptr);
}

// Round 7
// 649.380 us; speedup vs baseline: 1.0473x; 1.0473x over previous
//
#include <hip/hip_runtime.h>
#include <math.h>

typedef __attribute__((ext_vector_type(8))) short short8;
typedef __attribute__((ext_vector_type(4))) float f32x4;

namespace {
constexpr int B_ = 8;
constexpr int N_ = 2048;
constexpr int D_ = 1024;
constexpr float NEGV = -1.0e9f;
}

__device__ __forceinline__ unsigned short f2bf(float x) {
    union { float f; unsigned u; } v; v.f = x;
    unsigned u = v.u + 0x7fffu + ((v.u >> 16) & 1u);
    return (unsigned short)(u >> 16);
}

// ---------------------------------------------------------------------------
// Per-batch valid lengths from the prefix mask (uint8 or int32 layout).
// ---------------------------------------------------------------------------
__global__ __launch_bounds__(256)
void k_lengths(const unsigned char* __restrict__ mask, int* __restrict__ L)
{
    const int b = blockIdx.x;
    const int t = threadIdx.x;
    const bool u8 = (mask[1] != 0);
    int cnt = 0;
    if (u8) {
        for (int n = t; n < N_; n += 256)
            cnt += (mask[(size_t)b * N_ + n] != 0) ? 1 : 0;
    } else {
        const int* mi = (const int*)mask;
        for (int n = t; n < N_; n += 256)
            cnt += (mi[(size_t)b * N_ + n] != 0) ? 1 : 0;
    }
    __shared__ int red[256];
    red[t] = cnt;
    __syncthreads();
    for (int s = 128; s > 0; s >>= 1) {
        if (t < s) red[t] += red[t + s];
        __syncthreads();
    }
    if (t == 0) L[b] = red[0];
}

// ---------------------------------------------------------------------------
// f32 -> bf16 conversion (with optional scale), 1 float4 per thread.
// ---------------------------------------------------------------------------
__global__ __launch_bounds__(256)
void convert_bf16(const float* __restrict__ in, unsigned short* __restrict__ out,
                  int n4, float alpha)
{
    const int i = blockIdx.x * 256 + threadIdx.x;
    if (i >= n4) return;
    const float4 v = ((const float4*)in)[i];
    ushort4 o;
    o.x = f2bf(v.x * alpha); o.y = f2bf(v.y * alpha);
    o.z = f2bf(v.z * alpha); o.w = f2bf(v.w * alpha);
    ((ushort4*)out)[i] = o;
}

// ---------------------------------------------------------------------------
// 128x128 double-buffered bf16 MFMA NT-GEMM: C[m][n] = sum_k A[m][k]*B[n][k]
// 256 threads (4 waves, 2x2 of 64x64), BK=32, 16x16x32 MFMA,
// global_load_lds width-16 staging, 32 KiB LDS (2 bufs).
//
// ROUND-7 rationale: rounds 3-6 showed the 256^2 / 1-block-per-CU 2-phase
// structure is pinned at ~800 TF: all waves barrier-lock into the same
// resource phase and there is no second block on the CU to fill the drain
// windows (m233: stage+vmcnt+barrier = ~72% of the 2-phase critical path).
// The 2-barrier structure's measured tile-space is 128^2=912 > 256^2=792 TF
// (m103/m112): the win comes from >=3 blocks/CU cross-block overlap (m114),
// not from within-block scheduling. So: 128^2 tile, small LDS, modest VGPR,
// launch_bounds(256,3); stage(T+1) -> compute(T) -> one __syncthreads per
// K-tile (the syncthreads' vmcnt0+lgkm0 drain seals both dbuf hazards).
// No setprio (m190: hurts lockstep GEMM).
//
// LDS geometry (verified in rounds 0-1, 0 bank conflicts): row = 32 shorts
// (64 B). 16-B segment s_log of row m stored at phys seg s_log ^ ((m>>1)&3).
// Staging pre-swizzles the GLOBAL source seg so LDS dest stays linear.
// Fragment ds_read_b128 for lane (q=lane>>4, r=lane&15) reads phys seg
// q ^ ((r>>1)&3) -> conflict-free.
//
// OUT_MODE: 0 = f32, 1 = bf16, 2 = f32 with prefix mask (logits):
//   m0 >= Lb -> return, NO writes (softmax writes those rows whole);
//   n0 >= Lb -> NEGV fill, no compute;
//   else compute, epilogue masks per element.
// XCD swizzle: bijective chunking (total%8==0), n-fastest within chunk.
// ---------------------------------------------------------------------------
template <int OUT_MODE>
__global__ __launch_bounds__(256, 3)
void gemm_nt_128(const unsigned short* __restrict__ A, int lda, long strideA,
                 const unsigned short* __restrict__ Bm, int ldb, long strideB,
                 void* __restrict__ Cout, int ldc, long strideC,
                 int K, const int* __restrict__ Lp)
{
    __shared__ __attribute__((aligned(16))) short As[2][128 * 32];
    __shared__ __attribute__((aligned(16))) short Bs[2][128 * 32];

    const int tid  = threadIdx.x;
    const int lane = tid & 63;
    const int wave = tid >> 6;

    // ---- XCD-aware bijective block swizzle (n-fastest within chunk) ----
    const unsigned gx   = gridDim.x;
    const unsigned gxy  = gx * gridDim.y;
    const unsigned total = gxy * gridDim.z;
    const unsigned orig = blockIdx.x + gx * blockIdx.y + gxy * blockIdx.z;
    unsigned wg = orig;
    if ((total & 7u) == 0u)
        wg = (orig & 7u) * (total >> 3) + (orig >> 3);
    const unsigned bz  = wg / gxy;
    const unsigned rem = wg - bz * gxy;
    const unsigned byy = rem / gx;
    const unsigned bxx = rem - byy * gx;

    const int b  = (int)bz;
    const int m0 = (int)byy * 128;
    const int n0 = (int)bxx * 128;

    int Lb = 0;
    if (OUT_MODE == 2) {
        Lb = Lp[b];
        if (m0 >= Lb) return;   // softmax writes these rows entirely (const)
        if (n0 >= Lb) {
            // masked columns of valid rows: NEGV fill, no compute
            float* C = (float*)Cout + (long)b * strideC;
            const float4 nv = make_float4(NEGV, NEGV, NEGV, NEGV);
            const int rl = tid >> 5;          // 0..7
            const int c4 = (tid & 31) * 4;    // 0..124
#pragma unroll
            for (int l = 0; l < 16; ++l)
                *(float4*)(C + (long)(m0 + l * 8 + rl) * ldc + n0 + c4) = nv;
            return;
        }
    }

    const unsigned short* Ab = A  + (long)b * strideA;
    const unsigned short* Bb = Bm + (long)b * strideB;

    // staging: chunk c covers 16B; physical (row = c>>2, phys seg = c&3).
    // pre-swizzled global segment = (c&3) ^ ((c>>3)&3); identical for
    // c and c+256, so one seg value serves both halves.
    const int rowL = tid >> 2;            // chunks 0..255  -> rows 0..63
    const int rowH = (tid + 256) >> 2;    // chunks 256..511-> rows 64..127
    const int seg  = (((tid & 3) ^ ((tid >> 3) & 3)) * 8);

    const unsigned short* gA0 = Ab + (long)(m0 + rowL) * lda + seg;
    const unsigned short* gA1 = Ab + (long)(m0 + rowH) * lda + seg;
    const unsigned short* gB0 = Bb + (long)(n0 + rowL) * ldb + seg;
    const unsigned short* gB1 = Bb + (long)(n0 + rowH) * ldb + seg;

    // wave-uniform LDS chunk bases (shorts, relative to buffer start)
    const int lA0o = (tid & ~63) * 8;
    const int lA1o = lA0o + 2048;

    const int q = lane >> 4, r = lane & 15;
    const int wm = (wave & 1) * 64, wn = (wave >> 1) * 64;
    const int sphys = (q ^ ((r >> 1) & 3)) * 8;   // swizzled fragment segment

    int pao[4], pbo[4];
#pragma unroll
    for (int t = 0; t < 4; ++t) {
        pao[t] = (wm + t * 16 + r) * 32 + sphys;
        pbo[t] = (wn + t * 16 + r) * 32 + sphys;
    }

    const int NT = K >> 5;

    f32x4 acc[4][4] = {};

#define STAGE(dd, kt) do {                                                     \
    __builtin_amdgcn_global_load_lds(                                          \
        (const __attribute__((address_space(1))) void*)(gA0 + (long)(kt) * 32),\
        (__attribute__((address_space(3))) void*)(&As[dd][lA0o]), 16, 0, 0);   \
    __builtin_amdgcn_global_load_lds(                                          \
        (const __attribute__((address_space(1))) void*)(gB0 + (long)(kt) * 32),\
        (__attribute__((address_space(3))) void*)(&Bs[dd][lA0o]), 16, 0, 0);   \
    __builtin_amdgcn_global_load_lds(                                          \
        (const __attribute__((address_space(1))) void*)(gA1 + (long)(kt) * 32),\
        (__attribute__((address_space(3))) void*)(&As[dd][lA1o]), 16, 0, 0);   \
    __builtin_amdgcn_global_load_lds(                                          \
        (const __attribute__((address_space(1))) void*)(gB1 + (long)(kt) * 32),\
        (__attribute__((address_space(3))) void*)(&Bs[dd][lA1o]), 16, 0, 0);   \
} while (0)

    // prologue: tile 0 -> buf 0
    STAGE(0, 0);
    __syncthreads();   // full vmcnt0+lgkm0 drain + barrier (compiler-emitted)

    for (int kt = 0; kt < NT; ++kt) {
        const int d = kt & 1;
        if (kt + 1 < NT) STAGE(d ^ 1, kt + 1);   // buf d^1 sealed at kt-1's sync

        short8 af[4], bf[4];
#pragma unroll
        for (int t = 0; t < 4; ++t) {
            af[t] = *(const short8*)&As[d][pao[t]];
            bf[t] = *(const short8*)&Bs[d][pbo[t]];
        }
#pragma unroll
        for (int mt = 0; mt < 4; ++mt)
#pragma unroll
            for (int nt = 0; nt < 4; ++nt)
                acc[mt][nt] = __builtin_amdgcn_mfma_f32_16x16x32_bf16(
                    af[mt], bf[nt], acc[mt][nt], 0, 0, 0);

        __syncthreads();   // seals this tile's reads + lands next tile's stage
    }

#undef STAGE

    // epilogue: C/D layout col = lane&15 (=r), row = (lane>>4)*4 + reg
    if (OUT_MODE == 1) {
        unsigned short* C = (unsigned short*)Cout + (long)b * strideC;
#pragma unroll
        for (int mt = 0; mt < 4; ++mt)
#pragma unroll
            for (int nt = 0; nt < 4; ++nt)
#pragma unroll
                for (int rr = 0; rr < 4; ++rr) {
                    const int grow = m0 + wm + mt * 16 + q * 4 + rr;
                    const int gcol = n0 + wn + nt * 16 + r;
                    C[(long)grow * ldc + gcol] = f2bf(acc[mt][nt][rr]);
                }
    } else if (OUT_MODE == 0) {
        float* C = (float*)Cout + (long)b * strideC;
#pragma unroll
        for (int mt = 0; mt < 4; ++mt)
#pragma unroll
            for (int nt = 0; nt < 4; ++nt)
#pragma unroll
                for (int rr = 0; rr < 4; ++rr) {
                    const int grow = m0 + wm + mt * 16 + q * 4 + rr;
                    const int gcol = n0 + wn + nt * 16 + r;
                    C[(long)grow * ldc + gcol] = acc[mt][nt][rr];
                }
    } else {
        float* C = (float*)Cout + (long)b * strideC;
#pragma unroll
        for (int mt = 0; mt < 4; ++mt)
#pragma unroll
            for (int nt = 0; nt < 4; ++nt)
#pragma unroll
                for (int rr = 0; rr < 4; ++rr) {
                    const int grow = m0 + wm + mt * 16 + q * 4 + rr;
                    const int gcol = n0 + wn + nt * 16 + r;
                    const float val = (grow < Lb && gcol < Lb) ? acc[mt][nt][rr] : NEGV;
                    C[(long)grow * ldc + gcol] = val;
                }
    }
}

// ---------------------------------------------------------------------------
// In-place row softmax over last dim (N_=2048). One block per row.
// Rows >= Lb are fully masked -> softmax is exactly 1/2048: write const,
// no read (the logits GEMM skips those tiles entirely).
// ---------------------------------------------------------------------------
__global__ __launch_bounds__(256)
void softmax_rows(float* __restrict__ Att, const int* __restrict__ Lp)
{
    const size_t row = blockIdx.x;
    const int i = (int)(row & (N_ - 1));
    const int b = (int)(row >> 11);
    float* p = Att + row * (size_t)N_;
    const int t = threadIdx.x;

    if (i >= Lp[b]) {
        const float c = 1.0f / 2048.0f;
        const float4 cv = make_float4(c, c, c, c);
        *(float4*)(p + t * 4)        = cv;
        *(float4*)(p + 1024 + t * 4) = cv;
        return;
    }

    float4 v0 = *(float4*)(p + t * 4);
    float4 v1 = *(float4*)(p + 1024 + t * 4);

    float mx = fmaxf(fmaxf(fmaxf(v0.x, v0.y), fmaxf(v0.z, v0.w)),
                     fmaxf(fmaxf(v1.x, v1.y), fmaxf(v1.z, v1.w)));
#pragma unroll
    for (int o = 32; o > 0; o >>= 1) mx = fmaxf(mx, __shfl_xor(mx, o, 64));

    __shared__ float red[8];
    const int wv = t >> 6;
    if ((t & 63) == 0) red[wv] = mx;
    __syncthreads();
    mx = fmaxf(fmaxf(red[0], red[1]), fmaxf(red[2], red[3]));

    float e[8];
    e[0] = expf(v0.x - mx); e[1] = expf(v0.y - mx);
    e[2] = expf(v0.z - mx); e[3] = expf(v0.w - mx);
    e[4] = expf(v1.x - mx); e[5] = expf(v1.y - mx);
    e[6] = expf(v1.z - mx); e[7] = expf(v1.w - mx);
    float s = ((e[0] + e[1]) + (e[2] + e[3])) + ((e[4] + e[5]) + (e[6] + e[7]));
#pragma unroll
    for (int o = 32; o > 0; o >>= 1) s += __shfl_xor(s, o, 64);
    if ((t & 63) == 0) red[4 + wv] = s;
    __syncthreads();
    const float inv = 1.0f / (red[4] + red[5] + red[6] + red[7]);

    *(float4*)(p + t * 4)        = make_float4(e[0] * inv, e[1] * inv, e[2] * inv, e[3] * inv);
    *(float4*)(p + 1024 + t * 4) = make_float4(e[4] * inv, e[5] * inv, e[6] * inv, e[7] * inv);
}

// ---------------------------------------------------------------------------
// att f32 [b][j][i] -> attT bf16 [b][i][j], 64x64 LDS tile transpose.
// ---------------------------------------------------------------------------
__global__ __launch_bounds__(256)
void transpose_att_bf16(const float* __restrict__ att, unsigned short* __restrict__ attT)
{
    __shared__ float tile[64][65];
    const int b  = blockIdx.z;
    const int j0 = blockIdx.y * 64;
    const int i0 = blockIdx.x * 64;
    const float* src = att + (long)b * N_ * N_;
    unsigned short* dst = attT + (long)b * N_ * N_;
    const int t = threadIdx.x;
#pragma unroll
    for (int l = 0; l < 4; ++l) {
        const int idx = t + l * 256;
        const int jj = idx >> 4;
        const int i4 = (idx & 15) * 4;
        const float4 v = *(const float4*)(src + (long)(j0 + jj) * N_ + i0 + i4);
        tile[i4 + 0][jj] = v.x;
        tile[i4 + 1][jj] = v.y;
        tile[i4 + 2][jj] = v.z;
        tile[i4 + 3][jj] = v.w;
    }
    __syncthreads();
#pragma unroll
    for (int l = 0; l < 4; ++l) {
        const int idx = t + l * 256;
        const int ii = idx >> 4;
        const int j4 = (idx & 15) * 4;
        ushort4 o;
        o.x = f2bf(tile[ii][j4 + 0]);
        o.y = f2bf(tile[ii][j4 + 1]);
        o.z = f2bf(tile[ii][j4 + 2]);
        o.w = f2bf(tile[ii][j4 + 3]);
        *(ushort4*)(dst + (long)(i0 + ii) * N_ + j0 + j4) = o;
    }
}

// ---------------------------------------------------------------------------
// V slice of QKV [16384 tokens][3072] (cols 2048..3071) -> VT bf16 [1024][16384]
// ---------------------------------------------------------------------------
__global__ __launch_bounds__(256)
void transpose_v_bf16(const unsigned short* __restrict__ qkv, unsigned short* __restrict__ vt)
{
    __shared__ unsigned short tile[64][68];
    const int j0 = blockIdx.x * 64;
    const int d0 = blockIdx.y * 64;
    const int t = threadIdx.x;
#pragma unroll
    for (int l = 0; l < 4; ++l) {
        const int idx = t + l * 256;
        const int jj = idx >> 4;
        const int d4 = (idx & 15) * 4;
        const ushort4 v = *(const ushort4*)(qkv + (long)(j0 + jj) * 3072 + 2048 + d0 + d4);
        tile[d4 + 0][jj] = v.x;
        tile[d4 + 1][jj] = v.y;
        tile[d4 + 2][jj] = v.z;
        tile[d4 + 3][jj] = v.w;
    }
    __syncthreads();
#pragma unroll
    for (int l = 0; l < 4; ++l) {
        const int idx = t + l * 256;
        const int dd = idx >> 4;
        const int j4 = (idx & 15) * 4;
        ushort4 o;
        o.x = tile[dd][j4 + 0];
        o.y = tile[dd][j4 + 1];
        o.z = tile[dd][j4 + 2];
        o.w = tile[dd][j4 + 3];
        *(ushort4*)(vt + (long)(d0 + dd) * 16384 + j0 + j4) = o;
    }
}

// ---------------------------------------------------------------------------
extern "C" void kernel_launch(void* const* d_in, const int* in_sizes, int n_in,
                              void* d_out, int out_size, void* d_ws, size_t ws_size,
                              hipStream_t stream)
{
    const float* x  = (const float*)d_in[0];
    const unsigned char* mask = (const unsigned char*)d_in[1];
    const float* Wq = (const float*)d_in[2];
    const float* Wk = (const float*)d_in[3];
    const float* Wv = (const float*)d_in[4];
    const float* Wo = (const float*)d_in[5];

    float* y   = (float*)d_out;                          // [B,N,D] f32
    float* att = (float*)d_out + (size_t)B_ * N_ * D_;   // [B,N,N] f32

    char* ws = (char*)d_ws;
    int* L = (int*)ws;
    unsigned short* Wqkvb = (unsigned short*)(ws + 256); // [3072,1024] (Q|K|V rows)
    unsigned short* Wob   = Wqkvb + 3145728;             // [1024,1024]
    unsigned short* xb    = Wob + 1048576;               // [16384,1024]
    unsigned short* QKVb  = xb + 16777216;               // [16384,3072]
    unsigned short* VT    = QKVb + 50331648;             // [1024,16384]
    unsigned short* attT  = QKVb;                        // [B,N,N] bf16 (reuses QKV)
    unsigned short* ctx   = xb;                          // [16384,1024] bf16 (reuses xb)

    const dim3 blk(256);
    const long NN = (long)N_ * N_;
    const long ND = (long)N_ * D_;
    const long NQ = (long)N_ * 3072;

    k_lengths<<<dim3(B_), blk, 0, stream>>>(mask, L);

    convert_bf16<<<dim3(16384), blk, 0, stream>>>(x,  xb,  4194304, 1.0f);
    convert_bf16<<<dim3(1024),  blk, 0, stream>>>(Wq, Wqkvb,           262144, 0.06f);
    convert_bf16<<<dim3(1024),  blk, 0, stream>>>(Wk, Wqkvb + 1048576, 262144, 1.0f);
    convert_bf16<<<dim3(1024),  blk, 0, stream>>>(Wv, Wqkvb + 2097152, 262144, 1.0f);
    convert_bf16<<<dim3(1024),  blk, 0, stream>>>(Wo, Wob,             262144, 1.0f);

    // Fused QKV = x @ [Wq*0.06 | Wk | Wv]^T -> [16384, 3072] bf16
    gemm_nt_128<1><<<dim3(24, 128, 1), blk, 0, stream>>>(
        xb, D_, 0, Wqkvb, D_, 0, QKVb, 3072, 0, D_, nullptr);

    // VT[d][b*N+j] = V[b*N+j][d]
    transpose_v_bf16<<<dim3(256, 16), blk, 0, stream>>>(QKVb, VT);

    // logits = Q K^T with prefix mask (f32 out into att region)
    gemm_nt_128<2><<<dim3(16, 16, B_), blk, 0, stream>>>(
        QKVb, 3072, NQ, QKVb + 1024, 3072, NQ, att, N_, NN, D_, L);

    softmax_rows<<<dim3(B_ * N_), blk, 0, stream>>>(att, L);

    // attT bf16 (reuses QKV space; Q/K/V all consumed by now)
    transpose_att_bf16<<<dim3(32, 32, B_), blk, 0, stream>>>(att, attT);

    // ctx[b][i][d] = sum_j attT[b][i][j] * VT[d][b*N + j]
    gemm_nt_128<1><<<dim3(8, 16, B_), blk, 0, stream>>>(
        attT, N_, NN, VT, B_ * N_, N_, ctx, D_, ND, N_, nullptr);

    // y = ctx Wo^T (f32 out)
    gemm_nt_128<0><<<dim3(8, 128, 1), blk, 0, stream>>>(
        ctx, D_, 0, Wob, D_, 0, y, D_, 0, D_, nullptr);
}